// Round 1
// baseline (2786.911 us; speedup 1.0000x reference)
//
#include <hip/hip_runtime.h>
#include <math.h>

typedef unsigned short u16;
typedef unsigned int u32;

#define PI_F 3.14159265358979323846f

__device__ __forceinline__ float bf2f(u16 u){ union{u32 i; float f;} v; v.i=((u32)u)<<16; return v.f; }
__device__ __forceinline__ u16 f2bf(float f){ union{u32 i; float f;} v; v.f=f; u32 r=v.i+0x7fffu+((v.i>>16)&1u); return (u16)(r>>16); }
__device__ __forceinline__ float sigf(float x){ return 1.0f/(1.0f+expf(-x)); }

// ---------------- conv1: img (B,2,64,64) ch -> bf16 (B,64,64,64) ----------------
__global__ __launch_bounds__(256) void conv1_kernel(
    const float* __restrict__ imgp, int ch,
    const float* __restrict__ w1, const float* __restrict__ b1,
    u16* __restrict__ out)
{
  int b = blockIdx.y, tile = blockIdx.x;
  int ty0 = (tile>>2)<<4, tx0 = (tile&3)<<4;
  int tid = threadIdx.x;
  __shared__ float patch[18*18];
  __shared__ float wsm[576];
  const float* ib = imgp + (((size_t)b*2 + ch)<<12);
  for (int e=tid; e<324; e+=256){
    int py = e/18, px = e - py*18;
    int gy = ty0+py-1, gx = tx0+px-1;
    float v = 0.f;
    if (gy>=0 && gy<64 && gx>=0 && gx<64) v = ib[(gy<<6)+gx];
    patch[e] = v;
  }
  for (int e=tid; e<576; e+=256) wsm[e] = w1[e];
  __syncthreads();
  int ty = tid>>4, tx = tid&15;
  float p[9];
  #pragma unroll
  for (int ky=0;ky<3;ky++)
    #pragma unroll
    for (int kx=0;kx<3;kx++) p[ky*3+kx] = patch[(ty+ky)*18 + tx+kx];
  size_t obase = ((size_t)b<<18) + ((size_t)(ty0+ty)<<6) + (size_t)(tx0+tx);
  for (int oc=0; oc<64; oc++){
    float acc = b1[oc];
    #pragma unroll
    for (int k=0;k<9;k++) acc += wsm[oc*9+k]*p[k];
    out[obase + ((size_t)oc<<12)] = f2bf(acc);
  }
}

// ---------------- per-channel sum/sumsq over (B,H,W) of bf16 buf ----------------
__global__ __launch_bounds__(256) void stats_kernel(const u16* __restrict__ buf, float* __restrict__ st)
{
  int c = blockIdx.x, b0 = blockIdx.y*2;
  int tid = threadIdx.x;
  float s=0.f, s2=0.f;
  for (int r=0;r<2;r++){
    const u16* p = buf + ((((size_t)(b0+r)<<6) + (size_t)c)<<12);
    for (int k=tid;k<4096;k+=256){ float v=bf2f(p[k]); s+=v; s2+=v*v; }
  }
  #pragma unroll
  for (int off=32; off>0; off>>=1){ s += __shfl_down(s, off, 64); s2 += __shfl_down(s2, off, 64); }
  __shared__ float rs[4], rs2[4];
  int wid = tid>>6;
  if ((tid&63)==0){ rs[wid]=s; rs2[wid]=s2; }
  __syncthreads();
  if (tid==0){
    atomicAdd(&st[c],    rs[0]+rs[1]+rs[2]+rs[3]);
    atomicAdd(&st[64+c], rs2[0]+rs2[1]+rs2[2]+rs2[3]);
  }
}

// ---------------- BN apply (+optional residual) + ReLU, in-place on bf16 ----------------
__global__ __launch_bounds__(256) void bnapply_kernel(
    u16* __restrict__ buf, const float* __restrict__ st,
    const float* __restrict__ gam, const float* __restrict__ bet,
    const float* __restrict__ imgp, int ch, int addres)
{
  size_t i8 = (size_t)blockIdx.x*256 + threadIdx.x;
  size_t e0 = i8*8;
  int c = (int)((e0>>12)&63);
  int b = (int)(e0>>18);
  const float invN = 1.0f/524288.0f;
  float mean = st[c]*invN;
  float var  = st[64+c]*invN - mean*mean;
  float sc = gam[c]*rsqrtf(var+1e-5f);
  float sh = bet[c] - mean*sc;
  uint4 raw = *(const uint4*)(buf+e0);
  float v[8];
  v[0]=bf2f((u16)(raw.x&0xffff)); v[1]=bf2f((u16)(raw.x>>16));
  v[2]=bf2f((u16)(raw.y&0xffff)); v[3]=bf2f((u16)(raw.y>>16));
  v[4]=bf2f((u16)(raw.z&0xffff)); v[5]=bf2f((u16)(raw.z>>16));
  v[6]=bf2f((u16)(raw.w&0xffff)); v[7]=bf2f((u16)(raw.w>>16));
  if (addres){
    size_t hw = e0 & 4095;
    const float* rp = imgp + (((size_t)b*2+ch)<<12) + hw;
    #pragma unroll
    for (int k=0;k<8;k++) v[k] = v[k]*sc + sh + rp[k];
  } else {
    #pragma unroll
    for (int k=0;k<8;k++) v[k] = v[k]*sc + sh;
  }
  #pragma unroll
  for (int k=0;k<8;k++) v[k] = fmaxf(v[k], 0.f);
  uint4 o;
  o.x = (u32)f2bf(v[0]) | ((u32)f2bf(v[1])<<16);
  o.y = (u32)f2bf(v[2]) | ((u32)f2bf(v[3])<<16);
  o.z = (u32)f2bf(v[4]) | ((u32)f2bf(v[5])<<16);
  o.w = (u32)f2bf(v[6]) | ((u32)f2bf(v[7])<<16);
  *(uint4*)(buf+e0) = o;
}

// ---------------- conv2: bf16 (B,64,64,64) -> bf16 (B,64,64,64), +bias ----------------
__global__ __launch_bounds__(256) void conv2_kernel(
    const u16* __restrict__ in, const float* __restrict__ w2,
    const float* __restrict__ b2, u16* __restrict__ out)
{
  int b = blockIdx.y, tile = blockIdx.x;
  int ty0 = (tile>>2)<<4, tx0 = (tile&3)<<4;
  int tid = threadIdx.x;
  int ocg = tid>>4, pxg = tid&15;
  int py0 = (pxg>>2)<<2, px0 = (pxg&3)<<2;
  __shared__ float patch[18*18];
  __shared__ float wsm[576];
  float acc[64];
  #pragma unroll
  for (int i=0;i<64;i++) acc[i]=0.f;
  for (int ic=0; ic<64; ic++){
    const u16* ibase = in + (((size_t)(b*64+ic))<<12);
    for (int e=tid; e<324; e+=256){
      int py = e/18, px = e - py*18;
      int gy = ty0+py-1, gx = tx0+px-1;
      float v = 0.f;
      if (gy>=0 && gy<64 && gx>=0 && gx<64) v = bf2f(ibase[(gy<<6)+gx]);
      patch[e] = v;
    }
    for (int e=tid; e<576; e+=256){
      int oc = e/9, k = e - oc*9;
      wsm[e] = w2[(size_t)oc*576 + ic*9 + k];
    }
    __syncthreads();
    float pr[36];
    #pragma unroll
    for (int r=0;r<6;r++)
      #pragma unroll
      for (int cc=0;cc<6;cc++) pr[r*6+cc] = patch[(py0+r)*18 + px0+cc];
    #pragma unroll
    for (int o=0;o<4;o++){
      float wr[9];
      #pragma unroll
      for (int k=0;k<9;k++) wr[k] = wsm[(ocg*4+o)*9 + k];
      #pragma unroll
      for (int r=0;r<4;r++)
        #pragma unroll
        for (int cc=0;cc<4;cc++){
          float s = acc[o*16 + r*4 + cc];
          #pragma unroll
          for (int ky=0;ky<3;ky++)
            #pragma unroll
            for (int kx=0;kx<3;kx++)
              s += wr[ky*3+kx]*pr[(r+ky)*6 + cc+kx];
          acc[o*16 + r*4 + cc] = s;
        }
    }
    __syncthreads();
  }
  #pragma unroll
  for (int o=0;o<4;o++){
    int oc = ocg*4+o;
    float bias = b2[oc];
    #pragma unroll
    for (int r=0;r<4;r++){
      ushort4 stv;
      stv.x = f2bf(acc[o*16+r*4+0]+bias);
      stv.y = f2bf(acc[o*16+r*4+1]+bias);
      stv.z = f2bf(acc[o*16+r*4+2]+bias);
      stv.w = f2bf(acc[o*16+r*4+3]+bias);
      *(ushort4*)&out[(((size_t)(b*64+oc))<<12) + ((size_t)(ty0+py0+r)<<6) + (size_t)(tx0+px0)] = stv;
    }
  }
}

// ---------------- per-turn: glimpser linear + tanh + Cauchy filterbanks ----------------
__global__ __launch_bounds__(64) void params_kernel(
    const float* __restrict__ Hx,
    const float* __restrict__ gw, const float* __restrict__ gb,
    float* __restrict__ FhT, float* __restrict__ Fw)
{
  int b = blockIdx.x, lane = threadIdx.x;
  float h0 = Hx[b*128+lane], h1 = Hx[b*128+64+lane];
  float gpv[3];
  #pragma unroll
  for (int k=0;k<3;k++){
    float p = h0*gw[k*128+lane] + h1*gw[k*128+64+lane];
    #pragma unroll
    for (int off=32; off>0; off>>=1) p += __shfl_down(p, off, 64);
    float tot = __shfl(p, 0, 64);
    gpv[k] = tanhf(tot + gb[k]);
  }
  float ad = fabsf(gpv[2]);
  float delta = 8.0f*(1.0f-ad);
  float gamma = expf(1.0f-2.0f*ad);
  float inv_pg = 1.0f/(PI_F*gamma);
  float fi = (float)lane;
  float ctr = 31.5f*(gpv[0]+1.0f);
  float fh[8];
  #pragma unroll
  for (int g=0; g<8; g++){
    float mu = ctr + delta*((float)g - 3.5f);
    float u = (fi - mu)/gamma;
    float f = inv_pg/(1.0f+u*u);
    float s = f;
    #pragma unroll
    for (int off=32; off>0; off>>=1) s += __shfl_down(s, off, 64);
    s = __shfl(s, 0, 64);
    fh[g] = f/(s + 1e-4f);
  }
  float4* o = (float4*)(FhT + (((size_t)b<<6) + lane)*8);
  o[0] = make_float4(fh[0],fh[1],fh[2],fh[3]);
  o[1] = make_float4(fh[4],fh[5],fh[6],fh[7]);
  ctr = 31.5f*(gpv[1]+1.0f);
  #pragma unroll
  for (int w=0; w<8; w++){
    float mu = ctr + delta*((float)w - 3.5f);
    float u = (fi - mu)/gamma;
    float f = inv_pg/(1.0f+u*u);
    float s = f;
    #pragma unroll
    for (int off=32; off>0; off>>=1) s += __shfl_down(s, off, 64);
    s = __shfl(s, 0, 64);
    Fw[(((size_t)b<<3)+w)*64 + lane] = f/(s + 1e-4f);
  }
}

// ---------------- glimpse: gl[b,c] = Fh . img[b,c] . Fw^T -> flat (B,4096) ----------------
__global__ __launch_bounds__(64) void glimpse_kernel(
    const u16* __restrict__ img, const float* __restrict__ FhT,
    const float* __restrict__ Fw, float* __restrict__ flat)
{
  int c = blockIdx.x, b = blockIdx.y;
  int j = threadIdx.x;
  __shared__ __align__(16) float tsm[8*68];
  __shared__ __align__(16) float fwsm[8*68];
  for (int idx=j; idx<512; idx+=64){
    int w = idx>>6, col = idx&63;
    fwsm[w*68+col] = Fw[(((size_t)b<<3)+w)*64 + col];
  }
  const u16* ip = img + ((((size_t)b<<6)+(size_t)c)<<12) + j;
  const float4* fh4 = (const float4*)(FhT + ((size_t)b<<9));
  float t0=0,t1=0,t2=0,t3=0,t4=0,t5=0,t6=0,t7=0;
  #pragma unroll 8
  for (int i=0;i<64;i++){
    float v = bf2f(ip[(size_t)i<<6]);
    float4 a  = fh4[i*2];
    float4 bq = fh4[i*2+1];
    t0 += a.x*v;  t1 += a.y*v;  t2 += a.z*v;  t3 += a.w*v;
    t4 += bq.x*v; t5 += bq.y*v; t6 += bq.z*v; t7 += bq.w*v;
  }
  tsm[0*68+j]=t0; tsm[1*68+j]=t1; tsm[2*68+j]=t2; tsm[3*68+j]=t3;
  tsm[4*68+j]=t4; tsm[5*68+j]=t5; tsm[6*68+j]=t6; tsm[7*68+j]=t7;
  __syncthreads();
  int g = j>>3, w = j&7;
  float acc = 0.f;
  #pragma unroll
  for (int jq=0;jq<16;jq++){
    float4 tv = *(const float4*)&tsm[g*68 + jq*4];
    float4 wv = *(const float4*)&fwsm[w*68 + jq*4];
    acc += tv.x*wv.x + tv.y*wv.y + tv.z*wv.z + tv.w*wv.w;
  }
  flat[((size_t)b<<12) + (c<<6) + j] = acc;
}

// ---------------- gates GEMM: part[ks] += flat(128x4096) @ w_ih^T(512x4096), split-K ----------------
__global__ __launch_bounds__(256) void gemm_ih_kernel(
    const float* __restrict__ A, const float* __restrict__ Bw, float* __restrict__ part)
{
  int n0 = blockIdx.x*64;
  int k0 = blockIdx.y*128;
  __shared__ __align__(16) float Asm[16*132];
  __shared__ __align__(16) float Bsm[16*68];
  int tid = threadIdx.x;
  int tm = tid & 15, tn = tid >> 4;
  float acc[8][4];
  #pragma unroll
  for (int i=0;i<8;i++){
    #pragma unroll
    for (int jj=0;jj<4;jj++) acc[i][jj]=0.f;
  }
  for (int kt=0; kt<128; kt+=16){
    for (int e=tid; e<2048; e+=256){
      int m = e>>4, kk = e&15;
      Asm[kk*132+m] = A[(size_t)m*4096 + k0+kt+kk];
    }
    for (int e=tid; e<1024; e+=256){
      int n = e>>4, kk = e&15;
      Bsm[kk*68+n] = Bw[(size_t)(n0+n)*4096 + k0+kt+kk];
    }
    __syncthreads();
    #pragma unroll
    for (int kk=0;kk<16;kk++){
      float4 bv = *(const float4*)&Bsm[kk*68 + tn*4];
      float4 a0 = *(const float4*)&Asm[kk*132 + tm*8];
      float4 a1 = *(const float4*)&Asm[kk*132 + tm*8 + 4];
      float av[8] = {a0.x,a0.y,a0.z,a0.w,a1.x,a1.y,a1.z,a1.w};
      #pragma unroll
      for (int mm=0;mm<8;mm++){
        acc[mm][0] += av[mm]*bv.x;
        acc[mm][1] += av[mm]*bv.y;
        acc[mm][2] += av[mm]*bv.z;
        acc[mm][3] += av[mm]*bv.w;
      }
    }
    __syncthreads();
  }
  float* pp = part + (size_t)blockIdx.y*65536 + n0;
  #pragma unroll
  for (int mm=0;mm<8;mm++){
    int m = tm*8+mm;
    *(float4*)&pp[(size_t)m*512 + tn*4] = make_float4(acc[mm][0],acc[mm][1],acc[mm][2],acc[mm][3]);
  }
}

// ---------------- LSTM update: reduce partials + Hx@w_hh^T + biases, gate math ----------------
__global__ __launch_bounds__(128) void lstm_update_kernel(
    float* __restrict__ Hx, float* __restrict__ Cx,
    const float* __restrict__ part, const float* __restrict__ whhT,
    const float* __restrict__ b_ih, const float* __restrict__ b_hh)
{
  int b = blockIdx.x, hid = threadIdx.x;
  __shared__ float hs[128];
  hs[hid] = Hx[b*128+hid];
  __syncthreads();
  float g4[4];
  #pragma unroll
  for (int q=0;q<4;q++){
    int n = q*128+hid;
    float acc = b_ih[n] + b_hh[n];
    const float* pp = part + (size_t)b*512 + n;
    #pragma unroll 8
    for (int ks=0; ks<32; ks++) acc += pp[(size_t)ks*65536];
    const float* wp = whhT + n;
    #pragma unroll 8
    for (int k=0;k<128;k++) acc += hs[k]*wp[(size_t)k*512];
    g4[q] = acc;
  }
  float cx = Cx[b*128+hid];
  float cn = sigf(g4[1])*cx + sigf(g4[0])*tanhf(g4[2]);
  float hn = sigf(g4[3])*tanhf(cn);
  Cx[b*128+hid] = cn;
  Hx[b*128+hid] = hn;
}

__global__ __launch_bounds__(256) void transpose_whh_kernel(
    const float* __restrict__ whh, float* __restrict__ whhT)
{
  int idx = blockIdx.x*256 + threadIdx.x; // 65536 total
  int k = idx>>9, n = idx&511;
  whhT[idx] = whh[n*128 + k];
}

extern "C" void kernel_launch(void* const* d_in, const int* in_sizes, int n_in,
                              void* d_out, int out_size, void* d_ws, size_t ws_size,
                              hipStream_t stream)
{
  const float* imgp = (const float*)d_in[0];
  const float* w1  = (const float*)d_in[1];
  const float* b1  = (const float*)d_in[2];
  const float* g1  = (const float*)d_in[3];
  const float* be1 = (const float*)d_in[4];
  const float* w2  = (const float*)d_in[5];
  const float* b2  = (const float*)d_in[6];
  const float* g2  = (const float*)d_in[7];
  const float* be2 = (const float*)d_in[8];
  const float* wih = (const float*)d_in[9];
  const float* whh = (const float*)d_in[10];
  const float* bih = (const float*)d_in[11];
  const float* bhh = (const float*)d_in[12];
  const float* gw  = (const float*)d_in[13];
  const float* gb  = (const float*)d_in[14];

  char* ws = (char*)d_ws;
  u16* imgT   = (u16*)(ws + 0);          // test  resblock out, bf16 (B,64,64,64)
  u16* imgS   = (u16*)(ws + 67108864);   // support
  u16* tmp    = (u16*)(ws + 134217728);  // conv1/bn1 intermediate
  float* FhT  = (float*)(ws + 201326592);// (B,64,8)
  float* Fw   = (float*)(ws + 201588736);// (B,8,64)
  float* flat = (float*)(ws + 201850880);// (B,4096)
  float* part = (float*)(ws + 203948032);// (32,128,512)
  float* whhT = (float*)(ws + 212336640);// (128,512)
  float* Hx   = (float*)(ws + 212598784);
  float* Cx   = Hx + 16384;
  float* stats= Cx + 16384;              // 4 regions x 128 floats
  if (ws_size < 212731904ull) return;

  hipMemsetAsync(Hx, 0, (size_t)(16384+16384+512)*4, stream);
  transpose_whh_kernel<<<256,256,0,stream>>>(whh, whhT);

  for (int s=0; s<2; s++){
    int ch = (s==0)?1:0;                 // s=0: TEST (channel 1), s=1: SUPPORT (channel 0)
    u16* dst = (s==0)? imgT : imgS;
    conv1_kernel<<<dim3(16,128),256,0,stream>>>(imgp, ch, w1, b1, tmp);
    stats_kernel<<<dim3(64,64),256,0,stream>>>(tmp, stats + 128*(2*s));
    bnapply_kernel<<<16384,256,0,stream>>>(tmp, stats + 128*(2*s), g1, be1, imgp, ch, 0);
    conv2_kernel<<<dim3(16,128),256,0,stream>>>(tmp, w2, b2, dst);
    stats_kernel<<<dim3(64,64),256,0,stream>>>(dst, stats + 128*(2*s+1));
    bnapply_kernel<<<16384,256,0,stream>>>(dst, stats + 128*(2*s+1), g2, be2, imgp, ch, 1);
  }

  for (int t=0; t<16; t++){
    const u16* im = (t&1)? imgS : imgT;  // even turn -> test, odd -> support
    params_kernel<<<128,64,0,stream>>>(Hx, gw, gb, FhT, Fw);
    glimpse_kernel<<<dim3(64,128),64,0,stream>>>(im, FhT, Fw, flat);
    gemm_ih_kernel<<<dim3(8,32),256,0,stream>>>(flat, wih, part);
    lstm_update_kernel<<<128,128,0,stream>>>(Hx, Cx, part, whhT, bih, bhh);
  }

  hipMemcpyAsync(d_out, Hx, (size_t)16384*4, hipMemcpyDeviceToDevice, stream);
}

// Round 3
// 1974.523 us; speedup vs baseline: 1.4114x; 1.4114x over previous
//
#include <hip/hip_runtime.h>
#include <math.h>

typedef unsigned short u16;
typedef unsigned int u32;
typedef short bf16x8 __attribute__((ext_vector_type(8)));
typedef float f32x4 __attribute__((ext_vector_type(4)));

#define PI_F 3.14159265358979323846f

__device__ __forceinline__ float bf2f(u16 u){ union{u32 i; float f;} v; v.i=((u32)u)<<16; return v.f; }
__device__ __forceinline__ u16 f2bf(float f){ union{u32 i; float f;} v; v.f=f; u32 r=v.i+0x7fffu+((v.i>>16)&1u); return (u16)(r>>16); }
__device__ __forceinline__ float sigf(float x){ return 1.0f/(1.0f+expf(-x)); }

// ---------------- pack conv2 weights to bf16 fragment order: wpack[tap][chunk][oc][k=q*8+j] ----------------
__global__ __launch_bounds__(256) void wpack_kernel(const float* __restrict__ w2, u16* __restrict__ wpack)
{
  int e = blockIdx.x*256 + threadIdx.x;   // 36864 = 9*2*64*32
  if (e >= 36864) return;
  int k  = e & 31;
  int oc = (e>>5) & 63;
  int tc = e>>11;            // 0..17
  int tap = tc>>1, c = tc&1;
  int ic = c*32 + k;
  wpack[e] = f2bf(w2[(size_t)(oc*64 + ic)*9 + tap]);
}

// ---------------- conv1: img (B,2,64,64)[ch] f32 -> bf16 NHWC (B,64,64,64ch) (bias dropped: cancels in BN) ----------------
__global__ __launch_bounds__(256) void conv1_nhwc_kernel(
    const float* __restrict__ imgp, int ch,
    const float* __restrict__ w1, u16* __restrict__ out)
{
  int b = blockIdx.y, tile = blockIdx.x;
  int ty0 = (tile>>2)<<4, tx0 = (tile&3)<<4;
  int tid = threadIdx.x;
  __shared__ float patch[18*18];
  __shared__ float wsm[576];
  const float* ib = imgp + (((size_t)b*2 + ch)<<12);
  for (int e=tid; e<324; e+=256){
    int py = e/18, px = e - py*18;
    int gy = ty0+py-1, gx = tx0+px-1;
    float v = 0.f;
    if (gy>=0 && gy<64 && gx>=0 && gx<64) v = ib[(gy<<6)+gx];
    patch[e] = v;
  }
  for (int e=tid; e<576; e+=256) wsm[e] = w1[e];
  __syncthreads();
  int ty = tid>>4, tx = tid&15;
  float p[9];
  #pragma unroll
  for (int ky=0;ky<3;ky++)
    #pragma unroll
    for (int kx=0;kx<3;kx++) p[ky*3+kx] = patch[(ty+ky)*18 + tx+kx];
  u16* ob = out + ((((size_t)b<<12) + ((size_t)(ty0+ty)<<6) + (size_t)(tx0+tx))<<6);
  #pragma unroll
  for (int ocq=0; ocq<8; ocq++){
    u32 w4[4];
    #pragma unroll
    for (int pair=0; pair<4; pair++){
      float a0=0.f, a1=0.f;
      int oc0 = ocq*8 + pair*2;
      #pragma unroll
      for (int k=0;k<9;k++){ a0 += wsm[oc0*9+k]*p[k]; a1 += wsm[(oc0+1)*9+k]*p[k]; }
      w4[pair] = (u32)f2bf(a0) | ((u32)f2bf(a1)<<16);
    }
    ((uint4*)ob)[ocq] = make_uint4(w4[0],w4[1],w4[2],w4[3]);
  }
}

// ---------------- per-channel sum/sumsq over NHWC bf16 buf -> st[0..63]=sum, st[64..127]=sumsq ----------------
__global__ __launch_bounds__(256) void stats_nhwc_kernel(const u16* __restrict__ buf, float* __restrict__ st)
{
  int tid = threadIdx.x;
  int c8 = (tid&7)*8;
  int pg = tid>>3;                 // 0..31
  size_t p0 = (size_t)blockIdx.x*1024 + pg;
  float s[8], s2[8];
  #pragma unroll
  for (int k=0;k<8;k++){ s[k]=0.f; s2[k]=0.f; }
  for (int it=0; it<32; it++){
    size_t p = p0 + (size_t)it*32;
    uint4 v = *(const uint4*)(buf + (p<<6) + c8);
    u32 rw[4] = {v.x,v.y,v.z,v.w};
    #pragma unroll
    for (int d=0; d<4; d++){
      float f0 = bf2f((u16)(rw[d]&0xffff));
      float f1 = bf2f((u16)(rw[d]>>16));
      s[d*2]   += f0; s2[d*2]   += f0*f0;
      s[d*2+1] += f1; s2[d*2+1] += f1*f1;
    }
  }
  #pragma unroll
  for (int off=32; off>=8; off>>=1){
    #pragma unroll
    for (int k=0;k<8;k++){ s[k] += __shfl_down(s[k], off, 64); s2[k] += __shfl_down(s2[k], off, 64); }
  }
  __shared__ float sm[128];
  if (tid<128) sm[tid]=0.f;
  __syncthreads();
  if ((tid&63) < 8){
    int cb = tid&7;
    #pragma unroll
    for (int k=0;k<8;k++){
      atomicAdd(&sm[cb*8+k], s[k]);
      atomicAdd(&sm[64+cb*8+k], s2[k]);
    }
  }
  __syncthreads();
  if (tid<128) atomicAdd(&st[tid], sm[tid]);
}

// ---------------- BN apply (+optional residual) + ReLU, in-place on NHWC bf16 ----------------
__global__ __launch_bounds__(256) void bnapply_nhwc_kernel(
    u16* __restrict__ buf, const float* __restrict__ st,
    const float* __restrict__ gam, const float* __restrict__ bet,
    const float* __restrict__ imgp, int ch, int addres)
{
  size_t i8 = (size_t)blockIdx.x*256 + threadIdx.x;
  size_t e0 = i8*8;
  int cb = (int)(e0&63);
  size_t pos = e0>>6;
  const float invN = 1.0f/524288.0f;
  float res = 0.f;
  if (addres){
    int b = (int)(pos>>12);
    res = imgp[(((size_t)(b*2+ch))<<12) + (pos&4095)];
  }
  uint4 raw = *(const uint4*)(buf+e0);
  u32 rw[4] = {raw.x, raw.y, raw.z, raw.w};
  u32 ow[4];
  #pragma unroll
  for (int d=0; d<4; d++){
    u32 o = 0;
    #pragma unroll
    for (int h=0; h<2; h++){
      int c = cb + d*2 + h;
      float mean = st[c]*invN;
      float var  = st[64+c]*invN - mean*mean;
      float sc = gam[c]*rsqrtf(var+1e-5f);
      float sh = bet[c] - mean*sc;
      float v = bf2f((u16)((rw[d]>>(16*h))&0xffff))*sc + sh + res;
      v = fmaxf(v, 0.f);
      o |= ((u32)f2bf(v)) << (16*h);
    }
    ow[d] = o;
  }
  *(uint4*)(buf+e0) = make_uint4(ow[0],ow[1],ow[2],ow[3]);
}

// ---------------- conv2 MFMA: NHWC bf16 -> NHWC bf16 (bias dropped: cancels in BN) ----------------
// tile: 8 rows x 16 cols per block; 4 waves each own 2 rows (M=x 16-wide); N=oc (4 tiles); K = 9 taps x 2 ic-chunks of 32
__global__ __launch_bounds__(256) void conv2_mfma_kernel(
    const u16* __restrict__ in, const u16* __restrict__ wpack, u16* __restrict__ out)
{
  int b = blockIdx.y, tile = blockIdx.x;     // 32 tiles: 8 y-tiles x 4 x-tiles
  int y0 = (tile>>2)*8, x0 = (tile&3)*16;
  int tid = threadIdx.x;
  int w = tid>>6, lane = tid&63;
  int m = lane&15, q = lane>>4;

  __shared__ __align__(16) u16 patch[11520];  // [py10][cq8][px18][j8]

  for (int e=tid; e<1440; e+=256){
    int py = e/144; int rem = e - py*144;
    int px = rem>>3, cq = rem&7;
    int y = y0-1+py, x = x0-1+px;
    uint4 v = make_uint4(0,0,0,0);
    if (y>=0 && y<64 && x>=0 && x<64)
      v = *(const uint4*)(in + ((((size_t)b<<12) + ((size_t)y<<6) + (size_t)x)<<6) + cq*8);
    *(uint4*)(patch + ((((py<<3)+cq)*18 + px)<<3)) = v;
  }
  __syncthreads();

  f32x4 acc[2][4];
  #pragma unroll
  for (int mt=0;mt<2;mt++)
    #pragma unroll
    for (int nt=0;nt<4;nt++) acc[mt][nt] = (f32x4){0.f,0.f,0.f,0.f};

  #pragma unroll
  for (int tap=0; tap<9; tap++){
    const int dy = tap/3, dx = tap%3;
    #pragma unroll
    for (int c=0; c<2; c++){
      const int kk = tap*2 + c;
      bf16x8 bw[4];
      #pragma unroll
      for (int nt=0; nt<4; nt++)
        bw[nt] = *(const bf16x8*)(wpack + (size_t)(kk*64 + nt*16 + m)*32 + q*8);
      #pragma unroll
      for (int mt=0; mt<2; mt++){
        int py = 2*w + mt + dy;
        bf16x8 av = *(const bf16x8*)(patch + ((((py<<3) + (c<<2) + q)*18 + (m+dx))<<3));
        #pragma unroll
        for (int nt=0; nt<4; nt++)
          acc[mt][nt] = __builtin_amdgcn_mfma_f32_16x16x32_bf16(av, bw[nt], acc[mt][nt], 0,0,0);
      }
    }
  }
  __syncthreads();
  // epilogue: C/D mapping col(oc)=lane&15, row(x)=q*4+reg
  u16* etile = patch;                        // reuse: 128px x 64oc bf16 = 16KB
  #pragma unroll
  for (int mt=0; mt<2; mt++){
    int lp = (2*w+mt)*16 + q*4;
    #pragma unroll
    for (int nt=0; nt<4; nt++)
      #pragma unroll
      for (int r=0; r<4; r++)
        etile[(lp+r)*64 + nt*16 + m] = f2bf(acc[mt][nt][r]);
  }
  __syncthreads();
  // store full tile: 128 px x 64 oc; each thread does one (px, 32-ch half) = 4 uint4
  int lp = tid>>1, half = tid&1;
  int y = y0 + (lp>>4), x = x0 + (lp&15);
  uint4* gdst = (uint4*)(out + ((((size_t)b<<12) + ((size_t)y<<6) + (size_t)x)<<6) + half*32);
  const uint4* lsrc = (const uint4*)(etile + lp*64 + half*32);
  gdst[0] = lsrc[0];
  gdst[1] = lsrc[1];
  gdst[2] = lsrc[2];
  gdst[3] = lsrc[3];
}

// ---------------- glimpser linear + tanh + Cauchy filterbanks (per-lane helper) ----------------
__device__ __forceinline__ void compute_params_lane(
    int b, int lane, float h0, float h1,
    const float* __restrict__ gw, const float* __restrict__ gb,
    float* __restrict__ FhT, float* __restrict__ Fw)
{
  float gpv[3];
  #pragma unroll
  for (int k=0;k<3;k++){
    float p = h0*gw[k*128+lane] + h1*gw[k*128+64+lane];
    #pragma unroll
    for (int off=32; off>0; off>>=1) p += __shfl_down(p, off, 64);
    float tot = __shfl(p, 0, 64);
    gpv[k] = tanhf(tot + gb[k]);
  }
  float ad = fabsf(gpv[2]);
  float delta = 8.0f*(1.0f-ad);
  float gamma = expf(1.0f-2.0f*ad);
  float inv_pg = 1.0f/(PI_F*gamma);
  float fi = (float)lane;
  float ctr = 31.5f*(gpv[0]+1.0f);
  float fh[8];
  #pragma unroll
  for (int g=0; g<8; g++){
    float mu = ctr + delta*((float)g - 3.5f);
    float u = (fi - mu)/gamma;
    float f = inv_pg/(1.0f+u*u);
    float s = f;
    #pragma unroll
    for (int off=32; off>0; off>>=1) s += __shfl_down(s, off, 64);
    s = __shfl(s, 0, 64);
    fh[g] = f/(s + 1e-4f);
  }
  float4* o = (float4*)(FhT + (((size_t)b<<6) + lane)*8);
  o[0] = make_float4(fh[0],fh[1],fh[2],fh[3]);
  o[1] = make_float4(fh[4],fh[5],fh[6],fh[7]);
  ctr = 31.5f*(gpv[1]+1.0f);
  #pragma unroll
  for (int wv=0; wv<8; wv++){
    float mu = ctr + delta*((float)wv - 3.5f);
    float u = (fi - mu)/gamma;
    float f = inv_pg/(1.0f+u*u);
    float s = f;
    #pragma unroll
    for (int off=32; off>0; off>>=1) s += __shfl_down(s, off, 64);
    s = __shfl(s, 0, 64);
    Fw[(((size_t)b<<3)+wv)*64 + lane] = f/(s + 1e-4f);
  }
}

__global__ __launch_bounds__(64) void params_kernel(
    const float* __restrict__ Hx,
    const float* __restrict__ gw, const float* __restrict__ gb,
    float* __restrict__ FhT, float* __restrict__ Fw)
{
  int b = blockIdx.x, lane = threadIdx.x;
  compute_params_lane(b, lane, Hx[b*128+lane], Hx[b*128+64+lane], gw, gb, FhT, Fw);
}

// ---------------- glimpse NHWC: partial gl per (b, j-chunk of 16) -> part_gl[b][jc][c*64+g*8+w] ----------------
__global__ __launch_bounds__(256) void glimpse_nhwc_kernel(
    const u16* __restrict__ img, const float* __restrict__ FhT,
    const float* __restrict__ Fw, float* __restrict__ part_gl)
{
  int jc = blockIdx.x, b = blockIdx.y;
  int tid = threadIdx.x;
  int c = tid&63, s = tid>>6;
  __shared__ __align__(16) float fh_lds[512];   // [i][g]
  __shared__ __align__(16) float fw_lds[128];   // [jl][w]
  __shared__ __align__(16) float t_lds[16*8*64];// [jl][g][c]
  for (int e=tid; e<512; e+=256) fh_lds[e] = FhT[((size_t)b<<9)+e];
  if (tid<128){
    int jl = tid>>3, wv = tid&7;
    fw_lds[tid] = Fw[((((size_t)b<<3)+wv)<<6) + jc*16 + jl];
  }
  __syncthreads();
  float tacc[4][8];
  #pragma unroll
  for (int jj=0;jj<4;jj++)
    #pragma unroll
    for (int g=0;g<8;g++) tacc[jj][g]=0.f;
  const u16* ib = img + ((((size_t)b<<12) + (size_t)(jc*16 + s*4))<<6) + c;
  #pragma unroll 2
  for (int i=0;i<64;i++){
    f32x4 fa = *(const f32x4*)&fh_lds[i*8];
    f32x4 fb = *(const f32x4*)&fh_lds[i*8+4];
    #pragma unroll
    for (int jj=0;jj<4;jj++){
      float v = bf2f(ib[((size_t)i<<12) + (jj<<6)]);
      tacc[jj][0] += fa[0]*v; tacc[jj][1] += fa[1]*v;
      tacc[jj][2] += fa[2]*v; tacc[jj][3] += fa[3]*v;
      tacc[jj][4] += fb[0]*v; tacc[jj][5] += fb[1]*v;
      tacc[jj][6] += fb[2]*v; tacc[jj][7] += fb[3]*v;
    }
  }
  #pragma unroll
  for (int jj=0;jj<4;jj++)
    #pragma unroll
    for (int g=0;g<8;g++)
      t_lds[(((s*4+jj)<<3) + g)*64 + c] = tacc[jj][g];
  __syncthreads();
  float acc2[2][8];
  #pragma unroll
  for (int gi=0;gi<2;gi++)
    #pragma unroll
    for (int wv=0;wv<8;wv++) acc2[gi][wv]=0.f;
  #pragma unroll
  for (int jl=0; jl<16; jl++){
    float tv0 = t_lds[((jl<<3) + s*2)*64 + c];
    float tv1 = t_lds[((jl<<3) + s*2+1)*64 + c];
    f32x4 w0 = *(const f32x4*)&fw_lds[jl*8];
    f32x4 w1 = *(const f32x4*)&fw_lds[jl*8+4];
    acc2[0][0]+=tv0*w0[0]; acc2[0][1]+=tv0*w0[1]; acc2[0][2]+=tv0*w0[2]; acc2[0][3]+=tv0*w0[3];
    acc2[0][4]+=tv0*w1[0]; acc2[0][5]+=tv0*w1[1]; acc2[0][6]+=tv0*w1[2]; acc2[0][7]+=tv0*w1[3];
    acc2[1][0]+=tv1*w0[0]; acc2[1][1]+=tv1*w0[1]; acc2[1][2]+=tv1*w0[2]; acc2[1][3]+=tv1*w0[3];
    acc2[1][4]+=tv1*w1[0]; acc2[1][5]+=tv1*w1[1]; acc2[1][6]+=tv1*w1[2]; acc2[1][7]+=tv1*w1[3];
  }
  float* dst = part_gl + (((size_t)(b*4+jc))<<12) + c*64 + (s*2)*8;
  *(f32x4*)(dst+0)  = (f32x4){acc2[0][0],acc2[0][1],acc2[0][2],acc2[0][3]};
  *(f32x4*)(dst+4)  = (f32x4){acc2[0][4],acc2[0][5],acc2[0][6],acc2[0][7]};
  *(f32x4*)(dst+8)  = (f32x4){acc2[1][0],acc2[1][1],acc2[1][2],acc2[1][3]};
  *(f32x4*)(dst+12) = (f32x4){acc2[1][4],acc2[1][5],acc2[1][6],acc2[1][7]};
}

// ---------------- gates GEMM: part[ks] = (sum_jc part_gl)(128x4096) @ w_ih^T(512x4096), split-K ----------------
__global__ __launch_bounds__(256) void gemm_ih_kernel(
    const float* __restrict__ part_gl, const float* __restrict__ Bw, float* __restrict__ part)
{
  int n0 = blockIdx.x*64;
  int k0 = blockIdx.y*128;
  __shared__ __align__(16) float Asm[16*132];
  __shared__ __align__(16) float Bsm[16*68];
  int tid = threadIdx.x;
  int tm = tid & 15, tn = tid >> 4;
  float acc[8][4];
  #pragma unroll
  for (int i=0;i<8;i++)
    #pragma unroll
    for (int jj=0;jj<4;jj++) acc[i][jj]=0.f;
  for (int kt=0; kt<128; kt+=16){
    for (int e=tid; e<2048; e+=256){
      int mrow = e>>4, kk = e&15;
      const float* pg = part_gl + ((size_t)mrow<<14) + (k0+kt+kk);
      Asm[kk*132+mrow] = pg[0] + pg[4096] + pg[8192] + pg[12288];
    }
    for (int e=tid; e<1024; e+=256){
      int n = e>>4, kk = e&15;
      Bsm[kk*68+n] = Bw[(size_t)(n0+n)*4096 + k0+kt+kk];
    }
    __syncthreads();
    #pragma unroll
    for (int kk=0;kk<16;kk++){
      float4 bv = *(const float4*)&Bsm[kk*68 + tn*4];
      float4 a0 = *(const float4*)&Asm[kk*132 + tm*8];
      float4 a1 = *(const float4*)&Asm[kk*132 + tm*8 + 4];
      float av[8] = {a0.x,a0.y,a0.z,a0.w,a1.x,a1.y,a1.z,a1.w};
      #pragma unroll
      for (int mm=0;mm<8;mm++){
        acc[mm][0] += av[mm]*bv.x;
        acc[mm][1] += av[mm]*bv.y;
        acc[mm][2] += av[mm]*bv.z;
        acc[mm][3] += av[mm]*bv.w;
      }
    }
    __syncthreads();
  }
  float* pp = part + (size_t)blockIdx.y*65536 + n0;
  #pragma unroll
  for (int mm=0;mm<8;mm++){
    int mrow = tm*8+mm;
    *(float4*)&pp[(size_t)mrow*512 + tn*4] = make_float4(acc[mm][0],acc[mm][1],acc[mm][2],acc[mm][3]);
  }
}

// ---------------- LSTM update (+fused next-turn params) ----------------
__global__ __launch_bounds__(128) void lstm_update_kernel(
    float* __restrict__ Hx, float* __restrict__ Cx,
    const float* __restrict__ part, const float* __restrict__ whhT,
    const float* __restrict__ b_ih, const float* __restrict__ b_hh,
    const float* __restrict__ gw, const float* __restrict__ gb,
    float* __restrict__ FhT, float* __restrict__ Fw)
{
  int b = blockIdx.x, hid = threadIdx.x;
  __shared__ float hs[128];
  __shared__ float hs2[128];
  hs[hid] = Hx[b*128+hid];
  __syncthreads();
  float g4[4];
  #pragma unroll
  for (int qd=0;qd<4;qd++){
    int n = qd*128+hid;
    float acc = b_ih[n] + b_hh[n];
    const float* pp = part + (size_t)b*512 + n;
    #pragma unroll 8
    for (int ks=0; ks<32; ks++) acc += pp[(size_t)ks*65536];
    const float* wp = whhT + n;
    #pragma unroll 8
    for (int k=0;k<128;k++) acc += hs[k]*wp[(size_t)k*512];
    g4[qd] = acc;
  }
  float cx = Cx[b*128+hid];
  float cn = sigf(g4[1])*cx + sigf(g4[0])*tanhf(g4[2]);
  float hn = sigf(g4[3])*tanhf(cn);
  Cx[b*128+hid] = cn;
  Hx[b*128+hid] = hn;
  hs2[hid] = hn;
  __syncthreads();
  if (hid < 64)
    compute_params_lane(b, hid, hs2[hid], hs2[64+hid], gw, gb, FhT, Fw);
}

__global__ __launch_bounds__(256) void transpose_whh_kernel(
    const float* __restrict__ whh, float* __restrict__ whhT)
{
  int idx = blockIdx.x*256 + threadIdx.x; // 65536 total
  int k = idx>>9, n = idx&511;
  whhT[idx] = whh[n*128 + k];
}

extern "C" void kernel_launch(void* const* d_in, const int* in_sizes, int n_in,
                              void* d_out, int out_size, void* d_ws, size_t ws_size,
                              hipStream_t stream)
{
  const float* imgp = (const float*)d_in[0];
  const float* w1  = (const float*)d_in[1];
  // d_in[2] = conv1 bias: cancels through bn1 -> unused
  const float* g1  = (const float*)d_in[3];
  const float* be1 = (const float*)d_in[4];
  const float* w2  = (const float*)d_in[5];
  // d_in[6] = conv2 bias: cancels through bn2 -> unused
  const float* g2  = (const float*)d_in[7];
  const float* be2 = (const float*)d_in[8];
  const float* wih = (const float*)d_in[9];
  const float* whh = (const float*)d_in[10];
  const float* bih = (const float*)d_in[11];
  const float* bhh = (const float*)d_in[12];
  const float* gw  = (const float*)d_in[13];
  const float* gb  = (const float*)d_in[14];

  char* ws = (char*)d_ws;
  u16* imgT    = (u16*)(ws + 0);           // test resblock out, NHWC bf16 (B,64,64,64c)
  u16* imgS    = (u16*)(ws + 67108864);    // support
  u16* tmp     = (u16*)(ws + 134217728);   // conv1/bn1 intermediate, NHWC bf16
  // turn-loop scratch overlays tmp (tmp dead after conv phase):
  float* FhT     = (float*)(ws + 134217728); // (B,64,8)
  float* Fw      = (float*)(ws + 134479872); // (B,8,64)
  float* part_gl = (float*)(ws + 134742016); // (B,4,4096)
  float* part    = (float*)(ws + 143130624); // (32,128,512)
  float* whhT    = (float*)(ws + 151519232); // (128,512)
  u16*   wpack   = (u16*)  (ws + 201326592); // (9,2,64,32) bf16
  float* Hx      = (float*)(ws + 201400320);
  float* Cx      = (float*)(ws + 201465856);
  float* stats   = (float*)(ws + 201531392); // 4 regions x 128 f32
  if (ws_size < 201533440ull) return;

  hipMemsetAsync(Hx, 0, 65536+65536+2048, stream);   // Hx, Cx, stats contiguous
  wpack_kernel<<<144,256,0,stream>>>(w2, wpack);

  for (int s=0; s<2; s++){
    int ch = (s==0)?1:0;                   // s=0: TEST (channel 1), s=1: SUPPORT (channel 0)
    u16* dst = (s==0)? imgT : imgS;
    conv1_nhwc_kernel<<<dim3(16,128),256,0,stream>>>(imgp, ch, w1, tmp);
    stats_nhwc_kernel<<<512,256,0,stream>>>(tmp, stats + 128*(2*s));
    bnapply_nhwc_kernel<<<16384,256,0,stream>>>(tmp, stats + 128*(2*s), g1, be1, imgp, ch, 0);
    conv2_mfma_kernel<<<dim3(32,128),256,0,stream>>>(tmp, wpack, dst);
    stats_nhwc_kernel<<<512,256,0,stream>>>(dst, stats + 128*(2*s+1));
    bnapply_nhwc_kernel<<<16384,256,0,stream>>>(dst, stats + 128*(2*s+1), g2, be2, imgp, ch, 1);
  }

  // turn-loop scratch region becomes live only now
  transpose_whh_kernel<<<256,256,0,stream>>>(whh, whhT);
  params_kernel<<<128,64,0,stream>>>(Hx, gw, gb, FhT, Fw);   // Hx = 0 initial

  for (int t=0; t<16; t++){
    const u16* im = (t&1)? imgS : imgT;    // even turn -> test, odd -> support
    glimpse_nhwc_kernel<<<dim3(4,128),256,0,stream>>>(im, FhT, Fw, part_gl);
    gemm_ih_kernel<<<dim3(8,32),256,0,stream>>>(part_gl, wih, part);
    lstm_update_kernel<<<128,128,0,stream>>>(Hx, Cx, part, whhT, bih, bhh, gw, gb, FhT, Fw);
  }

  hipMemcpyAsync(d_out, Hx, (size_t)16384*4, hipMemcpyDeviceToDevice, stream);
}